// Round 1
// baseline (10359.935 us; speedup 1.0000x reference)
//
#include <hip/hip_runtime.h>
#include <math.h>

#define B_ 16
#define T_ 600
#define E_ 512
#define H_ 512
#define A_ 512
#define V_ 8000
#define STEPS_ 64
#define NW4 250     // k_logits workgroups (32 vocab rows each)
#define SOS_ 1

// ---------------------------------------------------------------------------
// init: zero hbuf (both parities), ctx, aw  (contiguous region)
// ---------------------------------------------------------------------------
__global__ __launch_bounds__(256) void k_init(float* base) {
    int tot = 2 * B_ * H_ + B_ * E_ + B_ * T_;
    for (int i = blockIdx.x * 256 + threadIdx.x; i < tot; i += gridDim.x * 256)
        base[i] = 0.f;
}

// ---------------------------------------------------------------------------
// Vv[b,t,a] = sum_d enc[b,t,d] * attn_V[a,d]      (one-time precompute)
// grid: 16 b * 40 t-chunks (15 t each) = 640 wgs
// ---------------------------------------------------------------------------
__global__ __launch_bounds__(256) void k_vv(const float* __restrict__ enc,
                                            const float* __restrict__ attn_V,
                                            float* __restrict__ Vv) {
    int wg = blockIdx.x;
    int b = wg / 40, t0 = (wg % 40) * 15;
    int tid = threadIdx.x;
    __shared__ __align__(16) float encL[15][E_];
    for (int i = tid; i < 15 * E_; i += 256) {
        int tl = i >> 9, d = i & 511;
        encL[tl][d] = enc[((size_t)(b * T_) + (t0 + tl)) * E_ + d];
    }
    __syncthreads();
    for (int half = 0; half < 2; ++half) {
        int a = tid + half * 256;
        const float4* wrow = reinterpret_cast<const float4*>(attn_V + (size_t)a * E_);
        float acc[15];
#pragma unroll
        for (int tl = 0; tl < 15; ++tl) acc[tl] = 0.f;
        for (int k = 0; k < E_ / 4; ++k) {
            float4 w = wrow[k];
#pragma unroll
            for (int tl = 0; tl < 15; ++tl) {
                float4 x = reinterpret_cast<const float4*>(&encL[tl][0])[k];
                acc[tl] += w.x * x.x + w.y * x.y + w.z * x.z + w.w * x.w;
            }
        }
        for (int tl = 0; tl < 15; ++tl)
            Vv[((size_t)(b * T_) + (t0 + tl)) * A_ + a] = acc[tl];
    }
}

// ---------------------------------------------------------------------------
// K1: finalize previous step's log_softmax + argmax, then GRU cell.
// grid: 16 b * 8 h-chunks = 128 wgs. doGru=0 for the final (s=64) call.
// ---------------------------------------------------------------------------
__global__ __launch_bounds__(256) void k_gru(const float* __restrict__ emb,
                                             const float* __restrict__ w_ih,
                                             const float* __restrict__ w_hh,
                                             const float* __restrict__ b_ih,
                                             const float* __restrict__ b_hh,
                                             float* __restrict__ hbuf,
                                             const float* __restrict__ ctx,
                                             const float* __restrict__ part,
                                             float* __restrict__ dout,
                                             int s, int doGru) {
    int wg = blockIdx.x;
    int b = wg >> 3, c = wg & 7;
    int tid = threadIdx.x;
    __shared__ float ra[256], ri[256], rs[256];
    __shared__ __align__(16) float xs[1024];
    __shared__ __align__(16) float hs[512];
    __shared__ float gxs[192], ghs[192];

    int tok = SOS_;
    if (s > 0) {
        // ---- finalize step s-1: global max/argmax + logZ over NW4 partials ----
        float m = -3.4e38f, si = 0.f, ii = 0.f;
        if (tid < NW4) {
            const float* rec = part + ((size_t)tid * B_ + b) * 4;
            m = rec[0]; si = rec[1]; ii = rec[2];
        }
        ra[tid] = m; ri[tid] = ii;
        __syncthreads();
        for (int off = 128; off; off >>= 1) {
            if (tid < off) {
                float am = ra[tid + off], ai = ri[tid + off];
                if (am > ra[tid] || (am == ra[tid] && ai < ri[tid])) { ra[tid] = am; ri[tid] = ai; }
            }
            __syncthreads();
        }
        float Mg = ra[0];
        float tokf = ri[0];
        __syncthreads();
        rs[tid] = si * expf(m - Mg);   // si==0 for inactive threads
        __syncthreads();
        for (int off = 128; off; off >>= 1) {
            if (tid < off) rs[tid] += rs[tid + off];
            __syncthreads();
        }
        float norm = Mg + logf(rs[0]);
        tok = (int)tokf;
        // normalize this wg's d_out slice of step s-1
        float* o = dout + ((size_t)(b * STEPS_ + (s - 1))) * V_;
        for (int v = c * 1000 + tid; v < (c + 1) * 1000; v += 256) o[v] -= norm;
        __syncthreads();
    }
    if (!doGru) return;

    // ---- GRU cell ----
    int p = s & 1;
    for (int i = tid; i < 1024; i += 256)
        xs[i] = (i < 512) ? emb[(size_t)tok * H_ + i] : ctx[b * E_ + (i - 512)];
    for (int i = tid; i < 512; i += 256)
        hs[i] = hbuf[((size_t)p * B_ + b) * H_ + i];
    __syncthreads();
    if (tid < 192) {
        int g = tid >> 6, i = tid & 63;
        int row = g * H_ + c * 64 + i;
        const float4* wr = reinterpret_cast<const float4*>(w_ih + (size_t)row * 1024);
        float acc = b_ih[row];
        for (int k = 0; k < 256; ++k) {
            float4 w = wr[k];
            float4 x = reinterpret_cast<const float4*>(xs)[k];
            acc += w.x * x.x + w.y * x.y + w.z * x.z + w.w * x.w;
        }
        gxs[tid] = acc;
        const float4* wh = reinterpret_cast<const float4*>(w_hh + (size_t)row * 512);
        float acc2 = b_hh[row];
        for (int k = 0; k < 128; ++k) {
            float4 w = wh[k];
            float4 x = reinterpret_cast<const float4*>(hs)[k];
            acc2 += w.x * x.x + w.y * x.y + w.z * x.z + w.w * x.w;
        }
        ghs[tid] = acc2;
    }
    __syncthreads();
    if (tid < 64) {
        int i = c * 64 + tid;
        float xr = gxs[tid], xz = gxs[64 + tid], xn = gxs[128 + tid];
        float hr = ghs[tid], hz = ghs[64 + tid], hn = ghs[128 + tid];
        float r = 1.f / (1.f + expf(-(xr + hr)));
        float z = 1.f / (1.f + expf(-(xz + hz)));
        float n = tanhf(xn + r * hn);
        float hp = hs[i];
        hbuf[((size_t)(p ^ 1) * B_ + b) * H_ + i] = (1.f - z) * n + z * hp;
    }
}

// ---------------------------------------------------------------------------
// K1b: wq[b,:] = h_new[b,:] @ attn_W.T    grid: 16 b * 4 a-chunks = 64 wgs
// ---------------------------------------------------------------------------
__global__ __launch_bounds__(256) void k_wq(const float* __restrict__ attn_W,
                                            const float* __restrict__ hbuf,
                                            float* __restrict__ wq, int s) {
    int wg = blockIdx.x;
    int b = wg >> 2, ac = wg & 3;
    int tid = threadIdx.x;
    __shared__ __align__(16) float hn[512];
    __shared__ float wpart[2][128];
    int p1 = (s & 1) ^ 1;
    for (int i = tid; i < 512; i += 256) hn[i] = hbuf[((size_t)p1 * B_ + b) * H_ + i];
    __syncthreads();
    int a = ac * 128 + (tid & 127), dh = tid >> 7;
    const float4* wr = reinterpret_cast<const float4*>(attn_W + (size_t)a * 512 + dh * 256);
    const float4* hv = reinterpret_cast<const float4*>(hn + dh * 256);
    float acc = 0.f;
    for (int k = 0; k < 64; ++k) {
        float4 w = wr[k];
        float4 x = hv[k];
        acc += w.x * x.x + w.y * x.y + w.z * x.z + w.w * x.w;
    }
    wpart[dh][tid & 127] = acc;
    __syncthreads();
    if (tid < 128) wq[b * A_ + ac * 128 + tid] = wpart[0][tid] + wpart[1][tid];
}

// ---------------------------------------------------------------------------
// K2: scores[b,t] = fc( tanh(wq + Vv + conv(aw) + b) )
// grid: 16 b * 10 t-chunks (60 t each) = 160 wgs
// ---------------------------------------------------------------------------
__global__ __launch_bounds__(256) void k_score(const float* __restrict__ Vv,
                                               const float* __restrict__ wq,
                                               const float* __restrict__ conv_w,
                                               const float* __restrict__ conv_b,
                                               const float* __restrict__ attn_b,
                                               const float* __restrict__ attn_fc_w,
                                               const float* __restrict__ attn_fc_b,
                                               const float* __restrict__ aw,
                                               float* __restrict__ score) {
    int wg = blockIdx.x;
    int b = wg / 10, tc = wg % 10;
    int tid = threadIdx.x;
    __shared__ float wqL[512], cw0[512], cw1[512], cw2[512], cbab[512], fcwL[512];
    for (int a = tid; a < 512; a += 256) {
        wqL[a] = wq[b * A_ + a];
        cw0[a] = conv_w[a * 3 + 0];
        cw1[a] = conv_w[a * 3 + 1];
        cw2[a] = conv_w[a * 3 + 2];
        cbab[a] = conv_b[a] + attn_b[a];
        fcwL[a] = attn_fc_w[a];
    }
    __syncthreads();
    int wv = tid >> 6, lane = tid & 63;
    float fcb = attn_fc_b[0];
    for (int tl = wv; tl < 60; tl += 4) {
        int t = tc * 60 + tl;
        float awm = (t > 0) ? aw[b * T_ + t - 1] : 0.f;
        float aw0 = aw[b * T_ + t];
        float awp = (t < T_ - 1) ? aw[b * T_ + t + 1] : 0.f;
        const float* vv = Vv + ((size_t)(b * T_) + t) * A_;
        float acc = 0.f;
#pragma unroll
        for (int q = 0; q < 8; ++q) {
            int a = lane + (q << 6);
            float conv = cbab[a] + cw0[a] * awm + cw1[a] * aw0 + cw2[a] * awp;
            float u = wqL[a] + vv[a] + conv;
            acc += tanhf(u) * fcwL[a];
        }
#pragma unroll
        for (int off = 32; off; off >>= 1) acc += __shfl_xor(acc, off, 64);
        if (lane == 0) score[b * T_ + t] = acc + fcb;
    }
}

// ---------------------------------------------------------------------------
// K3: softmax over t (per b, redundant per wg) + ctx chunk
// grid: 16 b * 8 e-chunks (64 e each) = 128 wgs
// ---------------------------------------------------------------------------
__global__ __launch_bounds__(256) void k_ctx(const float* __restrict__ score,
                                             const float* __restrict__ enc,
                                             float* __restrict__ aw,
                                             float* __restrict__ ctx) {
    int wg = blockIdx.x;
    int b = wg >> 3, ec = wg & 7;
    int tid = threadIdx.x;
    __shared__ float p[T_];
    __shared__ float red[256];
    __shared__ float red4[4][64];
    float lm = -3.4e38f;
    for (int t = tid; t < T_; t += 256) {
        float v = score[b * T_ + t];
        p[t] = v;
        lm = fmaxf(lm, v);
    }
    red[tid] = lm;
    __syncthreads();
    for (int off = 128; off; off >>= 1) {
        if (tid < off) red[tid] = fmaxf(red[tid], red[tid + off]);
        __syncthreads();
    }
    float M = red[0];
    __syncthreads();
    float ls = 0.f;
    for (int t = tid; t < T_; t += 256) {
        float e = expf(p[t] - M);
        p[t] = e;
        ls += e;
    }
    red[tid] = ls;
    __syncthreads();
    for (int off = 128; off; off >>= 1) {
        if (tid < off) red[tid] += red[tid + off];
        __syncthreads();
    }
    float S = red[0];
    __syncthreads();
    for (int t = tid; t < T_; t += 256) {
        float a_ = p[t] / S;
        p[t] = a_;
        if (ec == 0) aw[b * T_ + t] = a_;
    }
    __syncthreads();
    int lane = tid & 63, tg = tid >> 6;
    int e = ec * 64 + lane;
    float acc = 0.f;
    for (int t = tg; t < T_; t += 4)
        acc += p[t] * enc[((size_t)(b * T_) + t) * E_ + e];
    red4[tg][lane] = acc;
    __syncthreads();
    if (tg == 0)
        ctx[b * E_ + e] = red4[0][lane] + red4[1][lane] + red4[2][lane] + red4[3][lane];
}

// ---------------------------------------------------------------------------
// K4: logits = [h_new, ctx] @ fc_w.T + fc_b ; write raw logits to d_out,
// per-wg per-b partials {max, sumexp, argmax} to part.
// grid: NW4=250 wgs, 32 vocab rows each; thread (b = tid&15, j = tid>>4)
// ---------------------------------------------------------------------------
__global__ __launch_bounds__(256) void k_logits(const float* __restrict__ fc_w,
                                                const float* __restrict__ fc_b,
                                                const float* __restrict__ hbuf,
                                                const float* __restrict__ ctx,
                                                float* __restrict__ dout,
                                                float* __restrict__ part, int s) {
    int wg = blockIdx.x;
    int tid = threadIdx.x;
    __shared__ __align__(16) float outL[16][516];   // padded stride vs bank conflicts
    __shared__ float red[256][4];
    int p1 = (s & 1) ^ 1;
    int b = tid & 15, j = tid >> 4;
    int v0 = wg * 32 + 2 * j, v1 = v0 + 1;
    float acc0 = fc_b[v0], acc1 = fc_b[v1];
    for (int half = 0; half < 2; ++half) {
        __syncthreads();
        for (int i = tid; i < 16 * 512; i += 256) {
            int bb = i >> 9, kk = i & 511;
            outL[bb][kk] = half ? ctx[bb * E_ + kk]
                                : hbuf[((size_t)p1 * B_ + bb) * H_ + kk];
        }
        __syncthreads();
        const float4* w0 = reinterpret_cast<const float4*>(fc_w + (size_t)v0 * 1024 + half * 512);
        const float4* w1 = reinterpret_cast<const float4*>(fc_w + (size_t)v1 * 1024 + half * 512);
        const float4* ov = reinterpret_cast<const float4*>(&outL[b][0]);
        for (int k = 0; k < 128; ++k) {
            float4 o = ov[k];
            float4 a = w0[k];
            float4 c = w1[k];
            acc0 += a.x * o.x + a.y * o.y + a.z * o.z + a.w * o.w;
            acc1 += c.x * o.x + c.y * o.y + c.z * o.z + c.w * o.w;
        }
    }
    float* o = dout + ((size_t)(b * STEPS_ + s)) * V_;
    o[v0] = acc0;
    o[v1] = acc1;
    float bv, bi;
    if (acc0 >= acc1) { bv = acc0; bi = (float)v0; }
    else             { bv = acc1; bi = (float)v1; }
    float se = expf(acc0 - bv) + expf(acc1 - bv);
    red[tid][0] = bv; red[tid][1] = bi; red[tid][2] = se;
    __syncthreads();
    if (tid < 16) {
        float M = -3.4e38f, I = 0.f, S = 0.f;
        for (int jj = 0; jj < 16; ++jj) {
            float m = red[tid + 16 * jj][0], ii = red[tid + 16 * jj][1];
            if (m > M || (m == M && ii < I)) { M = m; I = ii; }
        }
        for (int jj = 0; jj < 16; ++jj)
            S += red[tid + 16 * jj][2] * expf(red[tid + 16 * jj][0] - M);
        float* pr = part + ((size_t)wg * B_ + tid) * 4;
        pr[0] = M; pr[1] = S; pr[2] = I;
    }
}

// ---------------------------------------------------------------------------
extern "C" void kernel_launch(void* const* d_in, const int* in_sizes, int n_in,
                              void* d_out, int out_size, void* d_ws, size_t ws_size,
                              hipStream_t stream) {
    const float* enc       = (const float*)d_in[0];
    const float* emb       = (const float*)d_in[1];
    const float* w_ih      = (const float*)d_in[2];
    const float* w_hh      = (const float*)d_in[3];
    const float* b_ih      = (const float*)d_in[4];
    const float* b_hh      = (const float*)d_in[5];
    const float* conv_w    = (const float*)d_in[6];
    const float* conv_b    = (const float*)d_in[7];
    const float* attn_W    = (const float*)d_in[8];
    const float* attn_V    = (const float*)d_in[9];
    const float* attn_fc_w = (const float*)d_in[10];
    const float* attn_fc_b = (const float*)d_in[11];
    const float* attn_b    = (const float*)d_in[12];
    const float* fc_w      = (const float*)d_in[13];
    const float* fc_b      = (const float*)d_in[14];

    float* ws    = (float*)d_ws;
    float* Vv    = ws;
    float* hbuf  = Vv + (size_t)B_ * T_ * A_;
    float* ctx   = hbuf + 2 * B_ * H_;
    float* aw    = ctx + B_ * E_;
    float* score = aw + B_ * T_;
    float* wq    = score + B_ * T_;
    float* part  = wq + B_ * A_;
    float* dout  = (float*)d_out;

    k_init<<<dim3(64), dim3(256), 0, stream>>>(hbuf);
    k_vv<<<dim3(640), dim3(256), 0, stream>>>(enc, attn_V, Vv);

    for (int s = 0; s < STEPS_; ++s) {
        k_gru<<<dim3(128), dim3(256), 0, stream>>>(emb, w_ih, w_hh, b_ih, b_hh,
                                                   hbuf, ctx, part, dout, s, 1);
        k_wq<<<dim3(64), dim3(256), 0, stream>>>(attn_W, hbuf, wq, s);
        k_score<<<dim3(160), dim3(256), 0, stream>>>(Vv, wq, conv_w, conv_b, attn_b,
                                                     attn_fc_w, attn_fc_b, aw, score);
        k_ctx<<<dim3(128), dim3(256), 0, stream>>>(score, enc, aw, ctx);
        k_logits<<<dim3(250), dim3(256), 0, stream>>>(fc_w, fc_b, hbuf, ctx, dout, part, s);
    }
    // final finalize (normalize step 63, no GRU)
    k_gru<<<dim3(128), dim3(256), 0, stream>>>(emb, w_ih, w_hh, b_ih, b_hh,
                                               hbuf, ctx, part, dout, STEPS_, 0);
}